// Round 6
// baseline (102.786 us; speedup 1.0000x reference)
//
#include <hip/hip_runtime.h>

typedef float v2f __attribute__((ext_vector_type(2)));

constexpr int H = 512, W = 512;   // fixed by the problem (4,3,512,512)
constexpr int K = 5;
constexpr int TR = 4;             // output rows per block
constexpr int SR = TR + 4;        // staged input rows (r0-2 .. r0+5)

__device__ __forceinline__ float rfl(float v) {
    union { float f; int i; } u; u.f = v;
    u.i = __builtin_amdgcn_readfirstlane(u.i);
    return u.f;
}

// map squared spatial distance {0,1,2,4,5,8} -> compact index 0..5
constexpr int idx6(int d2) {
    return d2 == 0 ? 0 : d2 == 1 ? 1 : d2 == 2 ? 2 : d2 == 4 ? 3 : d2 == 5 ? 4 : 5;
}

// Round-4 structure + LDS-pipe diet (the audited remaining waste):
//  - each wave's two tasks are rows rr and rr+2 of the same half; their
//    5-row windows overlap in 3 rows -> read the 7-row union ONCE and feed
//    both tasks (10 window builds -> 7).
//  - window = 1 ds_read_b128 (center 4 px) + 2 ds_read_b64 (2-px halos)
//    instead of 3 neighboring b128: LDS read traffic 480 B -> 256 B/thread.
//  - one LDS base VGPR; all reads use compile-time immediate offsets.
// Tap math identical to round 4 (packed f32, exact center tap) -> same absmax.
__global__ __launch_bounds__(256, 4) void bilateral_kernel(
    const float* __restrict__ x,
    const float* __restrict__ sk,
    const float* __restrict__ sigma_color,
    float* __restrict__ out)
{
    __shared__ float lds[SR][W];      // 16 KB

    int t = threadIdx.x;
    int wv = t >> 6;
    int l = t & 63;

    // 6 distinct spatial weights by symmetry: d2 = {0,1,2,4,5,8} at flat
    // positions {12, 7, 6, 2, 1, 0}. log2 once, broadcast to SGPRs.
    float lw[6];
    lw[0] = rfl(__builtin_amdgcn_logf(sk[12]));
    lw[1] = rfl(__builtin_amdgcn_logf(sk[7]));
    lw[2] = rfl(__builtin_amdgcn_logf(sk[6]));
    lw[3] = rfl(__builtin_amdgcn_logf(sk[2]));
    lw[4] = rfl(__builtin_amdgcn_logf(sk[1]));
    lw[5] = rfl(__builtin_amdgcn_logf(sk[0]));
    float sk12 = rfl(sk[12]);         // center tap weight, exact (exp(0)=1)

    float s = sigma_color[0];                          // wave-uniform
    float c2 = -1.4426950408889634f / (2.0f * s * s);  // -log2(e)/(2s^2)
    v2f c2v   = { c2, c2 };
    v2f sk12v = { sk12, sk12 };

    int plane = blockIdx.x >> 7;           // 12 planes (B*C)
    int r0 = (blockIdx.x & 127) << 2;      // first output row of tile
    const float* xp = x + (size_t)plane * (H * W);
    float* outp = out + (size_t)plane * (H * W);

    // ---- stage 8 rows x 512 cols as 16 (row,half) units, 4 per wave.
#pragma unroll
    for (int su = 0; su < 4; ++su) {
        int u = wv + (su << 2);            // 0..15
        int k = u >> 1, hh = u & 1;
        int gr = r0 - 2 + k;               // np 'reflect': -1 -> 1, H -> H-2
        gr = (gr < 0) ? -gr : gr;
        gr = (gr >= H) ? (2 * H - 2 - gr) : gr;
        int col = (hh << 8) + (l << 2);
        *(float4*)(&lds[k][col]) = *(const float4*)(xp + (gr << 9) + col);
    }
    __syncthreads();

    // ---- compute: wave wv -> task A = row r0+rrA, task B = row r0+rrA+2,
    // both at half hh. lds windows: A rows rrA..rrA+4, B rows rrA+2..rrA+6.
    int rrA = wv >> 1;                     // 0..1
    int hh  = wv & 1;
    int c   = (hh << 6) + l;               // chunk: cols 4c..4c+3
    bool le = (c == 0), re = (c == 127);
    int colm = c << 2;
    int colL = le ? 0 : colm - 2;          // b64 halo (8B-aligned); dummy at edge
    int colR = re ? 0 : colm + 4;

    const float* base = &lds[rrA][0];      // all reads: base + imm offset

    // center pixels of both tasks (lds rows rrA+2, rrA+4)
    float4 cA = *(const float4*)(base + 2 * W + colm);
    float4 cB = *(const float4*)(base + 4 * W + colm);
    v2f ccA0 = { cA.x, cA.y }, ccA1 = { cA.z, cA.w };
    v2f ccB0 = { cB.x, cB.y }, ccB1 = { cB.z, cB.w };

    v2f wsA0{0.f,0.f}, wsA1{0.f,0.f}, acA0{0.f,0.f}, acA1{0.f,0.f};
    v2f wsB0{0.f,0.f}, wsB1{0.f,0.f}, acB0{0.f,0.f}, acB1{0.f,0.f};

    auto taps = [&](int i, const float (&win)[8],
                    v2f cc0, v2f cc1, v2f& ws0, v2f& ws1, v2f& ac0, v2f& ac1) {
#pragma unroll
        for (int j = 0; j < K; ++j) {
            if (i == 2 && j == 2) {
                // center tap: d=0, weight = sk[12] exactly
                ws0 += sk12v;
                ws1 += sk12v;
                ac0 = __builtin_elementwise_fma(sk12v, cc0, ac0);
                ac1 = __builtin_elementwise_fma(sk12v, cc1, ac1);
            } else {
                const float lwv = lw[idx6((i - 2) * (i - 2) + (j - 2) * (j - 2))];
                v2f lsp = { lwv, lwv };
                v2f v0 = { win[j],     win[j + 1] };
                v2f v1 = { win[j + 2], win[j + 3] };
                v2f d0 = v0 - cc0;
                v2f d1 = v1 - cc1;
                v2f g0 = __builtin_elementwise_fma(d0 * c2v, d0, lsp);
                v2f g1 = __builtin_elementwise_fma(d1 * c2v, d1, lsp);
                v2f w0, w1;
                w0[0] = __builtin_amdgcn_exp2f(g0[0]);
                w0[1] = __builtin_amdgcn_exp2f(g0[1]);
                w1[0] = __builtin_amdgcn_exp2f(g1[0]);
                w1[1] = __builtin_amdgcn_exp2f(g1[1]);
                ws0 += w0;
                ws1 += w1;
                ac0 = __builtin_elementwise_fma(w0, v0, ac0);
                ac1 = __builtin_elementwise_fma(w1, v1, ac1);
            }
        }
    };

    // 7-row union, each row read once: 1 b128 + 2 b64, imm offsets (k static)
#pragma unroll
    for (int k = 0; k < 7; ++k) {
        const float* rp = base + k * W;
        float4 m = *(const float4*)(rp + colm);
        v2f aL = *(const v2f*)(rp + colL);
        v2f aR = *(const v2f*)(rp + colR);

        float win[8];
        win[0] = le ? m.z : aL[0];         // col -2 -> 2 at left edge
        win[1] = le ? m.y : aL[1];         // col -1 -> 1
        win[2] = m.x; win[3] = m.y; win[4] = m.z; win[5] = m.w;
        win[6] = re ? m.z : aR[0];         // col 512 -> 510 at right edge
        win[7] = re ? m.y : aR[1];         // col 513 -> 509

        if (k <= 4) taps(k,     win, ccA0, ccA1, wsA0, wsA1, acA0, acA1);
        if (k >= 2) taps(k - 2, win, ccB0, ccB1, wsB0, wsB1, acB0, acB1);
    }

    float4 oA, oB;
    oA.x = acA0[0] * __builtin_amdgcn_rcpf(wsA0[0] + 1e-8f);
    oA.y = acA0[1] * __builtin_amdgcn_rcpf(wsA0[1] + 1e-8f);
    oA.z = acA1[0] * __builtin_amdgcn_rcpf(wsA1[0] + 1e-8f);
    oA.w = acA1[1] * __builtin_amdgcn_rcpf(wsA1[1] + 1e-8f);
    oB.x = acB0[0] * __builtin_amdgcn_rcpf(wsB0[0] + 1e-8f);
    oB.y = acB0[1] * __builtin_amdgcn_rcpf(wsB0[1] + 1e-8f);
    oB.z = acB1[0] * __builtin_amdgcn_rcpf(wsB1[0] + 1e-8f);
    oB.w = acB1[1] * __builtin_amdgcn_rcpf(wsB1[1] + 1e-8f);
    *(float4*)(outp + ((size_t)(r0 + rrA)     << 9) + colm) = oA;
    *(float4*)(outp + ((size_t)(r0 + rrA + 2) << 9) + colm) = oB;
}

extern "C" void kernel_launch(void* const* d_in, const int* in_sizes, int n_in,
                              void* d_out, int out_size, void* d_ws, size_t ws_size,
                              hipStream_t stream) {
    const float* x  = (const float*)d_in[0];
    const float* sk = (const float*)d_in[1];
    const float* sc = (const float*)d_in[2];
    float* out = (float*)d_out;

    const int total = in_sizes[0];              // 3,145,728 elements
    const int blocks = total / (256 * 8);       // 1536 = 12 planes * 128 tiles
    bilateral_kernel<<<blocks, 256, 0, stream>>>(x, sk, sc, out);
}

// Round 7
// 78.290 us; speedup vs baseline: 1.3129x; 1.3129x over previous
//
#include <hip/hip_runtime.h>

typedef float v2f __attribute__((ext_vector_type(2)));

constexpr int H = 512, W = 512;   // fixed by the problem (4,3,512,512)
constexpr int K = 5;
constexpr int TR = 4;             // output rows per block
constexpr int SR = TR + 4;        // staged input rows (r0-2 .. r0+5)

__device__ __forceinline__ float rfl(float v) {
    union { float f; int i; } u; u.f = v;
    u.i = __builtin_amdgcn_readfirstlane(u.i);
    return u.f;
}

// map squared spatial distance {0,1,2,4,5,8} -> compact index 0..5
constexpr int idx6(int d2) {
    return d2 == 0 ? 0 : d2 == 1 ? 1 : d2 == 2 ? 2 : d2 == 4 ? 3 : d2 == 5 ? 4 : 5;
}

// async global->LDS, 16 B per lane. LDS dest must be wave-uniform base +
// lane*16 (m104) -- our staging layout is exactly that. Flat->AS3 via 32-bit
// truncation (gfx9+ LDS aperture trick, same as CK's amd_direct_load).
__device__ __forceinline__ void gload_lds16(const float* g, float* l) {
    __builtin_amdgcn_global_load_lds(
        (const __attribute__((address_space(1))) unsigned int*)(unsigned long long)g,
        (__attribute__((address_space(3))) unsigned int*)(unsigned int)(unsigned long long)l,
        16, 0, 0);
}

// Round-4 kernel (proven 77.1 us; round-5's merged-task variant spilled to
// scratch: WRITE_SIZE 105 MB vs 12.6 MB output, VGPR pinned at 64, 55 us)
// plus two register-neutral changes:
//  1. global_load_lds staging (no VGPR round-trip, async into LDS, one drain
//     at the barrier) -- compiler never auto-emits this.
//  2. Bijective XCD swizzle (1536 % 8 == 0): vertically adjacent tiles land
//     on the same XCD L2 and share 4 of their 8 staged rows -> halves cold
//     staging fetch (poison fill evicts L3 each iteration).
__global__ __launch_bounds__(256, 4) void bilateral_kernel(
    const float* __restrict__ x,
    const float* __restrict__ sk,
    const float* __restrict__ sigma_color,
    float* __restrict__ out)
{
    __shared__ float lds[SR][W];      // 16 KB

    int t = threadIdx.x;
    int wv = t >> 6;
    int l = t & 63;

    // 6 distinct spatial weights by symmetry: d2 = {0,1,2,4,5,8} at flat
    // positions {12, 7, 6, 2, 1, 0}. log2 once, broadcast to SGPRs.
    float lw[6];
    lw[0] = rfl(__builtin_amdgcn_logf(sk[12]));
    lw[1] = rfl(__builtin_amdgcn_logf(sk[7]));
    lw[2] = rfl(__builtin_amdgcn_logf(sk[6]));
    lw[3] = rfl(__builtin_amdgcn_logf(sk[2]));
    lw[4] = rfl(__builtin_amdgcn_logf(sk[1]));
    lw[5] = rfl(__builtin_amdgcn_logf(sk[0]));
    float sk12 = rfl(sk[12]);         // center tap weight, exact (exp(0)=1)

    float s = sigma_color[0];                          // wave-uniform
    float c2 = -1.4426950408889634f / (2.0f * s * s);  // -log2(e)/(2s^2)
    v2f c2v   = { c2, c2 };
    v2f sk12v = { sk12, sk12 };

    // XCD-aware bijective swizzle: grid 1536 = 8 XCDs x 192 contiguous tiles.
    int bid = blockIdx.x;
    int nb  = (bid & 7) * 192 + (bid >> 3);

    int plane = nb >> 7;                   // 12 planes (B*C)
    int r0 = (nb & 127) << 2;              // first output row of tile
    const float* xp = x + (size_t)plane * (H * W);
    float* outp = out + (size_t)plane * (H * W);

    // ---- stage 8 rows x 512 cols as 16 (row,half) units, 4 per wave.
    // Each unit: 64 lanes x 16 B direct global->LDS (async), drained by the
    // barrier below. k,hh wave-uniform; LDS addr = uniform base + l*16. ----
#pragma unroll
    for (int su = 0; su < 4; ++su) {
        int u = wv + (su << 2);            // 0..15
        int k = u >> 1, hh = u & 1;
        int gr = r0 - 2 + k;               // np 'reflect': -1 -> 1, H -> H-2
        gr = (gr < 0) ? -gr : gr;
        gr = (gr >= H) ? (2 * H - 2 - gr) : gr;
        int col = (hh << 8) + (l << 2);
        gload_lds16(xp + (gr << 9) + col, &lds[k][col]);
    }
    __syncthreads();

    // ---- compute: 8 tasks (4 rows x 2 halves); wave wv -> tasks wv, wv+4
#pragma unroll
    for (int ti = 0; ti < 2; ++ti) {
        int tk = wv + (ti << 2);           // 0..7
        int rr = tk >> 1, hh = tk & 1;     // output row r0+rr, half hh
        int c  = (hh << 6) + l;            // chunk: cols 4c..4c+3
        bool le = (c == 0), re = (c == 127);
        int cm1 = le ? 0   : c - 1;
        int cp1 = re ? 127 : c + 1;

        v2f cc0, cc1, ws0, ws1, ac0, ac1;
        ws0 = ws1 = ac0 = ac1 = (v2f){0.f, 0.f};
        cc0 = cc1 = (v2f){0.f, 0.f};

        constexpr int order[K] = {2, 0, 1, 3, 4};   // center row first
#pragma unroll
        for (int oi = 0; oi < K; ++oi) {
            const int i = order[oi];
            const float* rp = &lds[rr + i][0];

            float4 a = *(const float4*)(rp + (cm1 << 2));
            float4 m = *(const float4*)(rp + (c   << 2));
            float4 b = *(const float4*)(rp + (cp1 << 2));

            // window cols 4c-2 .. 4c+5
            float win[8];
            win[0] = le ? m.z : a.z;       // col -2 -> 2 at left edge
            win[1] = le ? m.y : a.w;       // col -1 -> 1
            win[2] = m.x; win[3] = m.y; win[4] = m.z; win[5] = m.w;
            win[6] = re ? m.z : b.x;       // col 512 -> 510 at right edge
            win[7] = re ? m.y : b.y;       // col 513 -> 509

            if (oi == 0) {                 // i==2: capture center pixels
                cc0 = (v2f){ win[2], win[3] };
                cc1 = (v2f){ win[4], win[5] };
            }

#pragma unroll
            for (int j = 0; j < K; ++j) {
                if (i == 2 && j == 2) {
                    // center tap: d=0, weight = sk[12] exactly
                    ws0 += sk12v;
                    ws1 += sk12v;
                    ac0 = __builtin_elementwise_fma(sk12v, cc0, ac0);
                    ac1 = __builtin_elementwise_fma(sk12v, cc1, ac1);
                } else {
                    const float lwv = lw[idx6((i - 2) * (i - 2) + (j - 2) * (j - 2))];
                    v2f lsp = { lwv, lwv };
                    v2f v0 = { win[j],     win[j + 1] };
                    v2f v1 = { win[j + 2], win[j + 3] };
                    v2f d0 = v0 - cc0;
                    v2f d1 = v1 - cc1;
                    v2f g0 = __builtin_elementwise_fma(d0 * c2v, d0, lsp);
                    v2f g1 = __builtin_elementwise_fma(d1 * c2v, d1, lsp);
                    v2f w0, w1;
                    w0[0] = __builtin_amdgcn_exp2f(g0[0]);
                    w0[1] = __builtin_amdgcn_exp2f(g0[1]);
                    w1[0] = __builtin_amdgcn_exp2f(g1[0]);
                    w1[1] = __builtin_amdgcn_exp2f(g1[1]);
                    ws0 += w0;
                    ws1 += w1;
                    ac0 = __builtin_elementwise_fma(w0, v0, ac0);
                    ac1 = __builtin_elementwise_fma(w1, v1, ac1);
                }
            }
        }

        float4 o;
        o.x = ac0[0] * __builtin_amdgcn_rcpf(ws0[0] + 1e-8f);
        o.y = ac0[1] * __builtin_amdgcn_rcpf(ws0[1] + 1e-8f);
        o.z = ac1[0] * __builtin_amdgcn_rcpf(ws1[0] + 1e-8f);
        o.w = ac1[1] * __builtin_amdgcn_rcpf(ws1[1] + 1e-8f);
        *(float4*)(outp + ((size_t)(r0 + rr) << 9) + (c << 2)) = o;
    }
}

extern "C" void kernel_launch(void* const* d_in, const int* in_sizes, int n_in,
                              void* d_out, int out_size, void* d_ws, size_t ws_size,
                              hipStream_t stream) {
    const float* x  = (const float*)d_in[0];
    const float* sk = (const float*)d_in[1];
    const float* sc = (const float*)d_in[2];
    float* out = (float*)d_out;

    const int total = in_sizes[0];              // 3,145,728 elements
    const int blocks = total / (256 * 8);       // 1536 = 12 planes * 128 tiles
    bilateral_kernel<<<blocks, 256, 0, stream>>>(x, sk, sc, out);
}